// Round 8
// baseline (100.369 us; speedup 1.0000x reference)
//
#include <hip/hip_runtime.h>

// out[b,o,y,x] = bias[o] + sum_{s<16,kh,kw} W[o,s,kh,kw] * X[b,(o+s)%64,y+kh,x+kw]
// MFMA: 9 banded 64x64 matrices, fp16. Band touches only 6 of 8 (oh,cs) 32x16
// blocks: oh0 -> cs{0,1,2}, oh1 -> cs{0,2,3} -> 27 fragments / o-half.

typedef _Float16 f16;
typedef _Float16 f16x8 __attribute__((ext_vector_type(8)));
typedef float    f32x16 __attribute__((ext_vector_type(16)));

constexpr int IN_H = 96, IN_W = 96, OUT_H = 94, OUT_W = 94;
constexpr int NCH = 64, NOC = 64, NSUB = 16, BATCH = 8;
constexpr int NSTRIP = BATCH * 3;                    // 24 (b,xg) column strips
constexpr int RUNS   = 48;                           // y-runs of 2 per strip (47 used + 1 pad)
constexpr int NBLK   = NSTRIP * RUNS * 2 / 4;        // 576 blocks (4 waves = 2 pairs each)
constexpr size_t A_BYTES  = 2ull * 27 * 64 * 16;     // 2 oh x 27 frags x 64 lanes x 16B
constexpr size_t XN_ELEMS = (size_t)BATCH * IN_H * IN_W * NCH;   // fp16 NHWC
constexpr size_t XN_OFF   = A_BYTES;
constexpr size_t WS_NEEDED = XN_OFF + XN_ELEMS * 2 + 1024;       // pad: x=96/97 halo reads

// ---- prologue 1: band matrices, A-frag lane layout, zero-blocks skipped ----
// A-frag (32x32x16): lane l holds row o=(l&31), k=(l>>5)*8+j.
__global__ void build_a_k(const float* __restrict__ W, f16* __restrict__ Ah)
{
    const int e = blockIdx.x * 256 + threadIdx.x;     // 2*27*64 = 3456 granules
    if (e >= 2 * 27 * 64) return;
    const int lane = e & 63;
    const int r    = e >> 6;          // oh*27 + khw*3 + j
    const int j    = r % 3;
    const int khw  = (r / 3) % 9;
    const int oh   = r / 27;
    const int cs   = oh ? (j == 0 ? 0 : j + 1) : j;   // oh0:{0,1,2} oh1:{0,2,3}
    const int kh = khw / 3, kw = khw % 3;
    const int o  = oh * 32 + (lane & 31);
    const int cb = cs * 16 + (lane >> 5) * 8;
    f16 v[8];
#pragma unroll
    for (int jj = 0; jj < 8; ++jj) {
        const int c = cb + jj;
        const int s = (c - o) & 63;
        v[jj] = (s < NSUB) ? (f16)W[((o * NSUB + s) * 3 + kh) * 3 + kw] : (f16)0.f;
    }
    *reinterpret_cast<f16x8*>(Ah + (size_t)e * 8) = *reinterpret_cast<f16x8*>(v);
}

// ---- prologue 2: NCHW fp32 -> NHWC fp16 (unchanged: controlled variable) ---
__global__ void transpose_k(const float* __restrict__ X, f16* __restrict__ Xn)
{
    const int id = blockIdx.x;                  // (b, y, xt)
    const int xt = id % 3;
    const int ym = id / 3;
    const int y  = ym % IN_H;
    const int b  = ym / IN_H;
    const int x  = xt * 32 + (threadIdx.x & 31);
    const int c0 = (threadIdx.x >> 5) * 8;
    const float* __restrict__ xp = X + (((size_t)(b * NCH + c0) * IN_H + y) * IN_W + x);
    f16 v[8];
#pragma unroll
    for (int i = 0; i < 8; ++i)
        v[i] = (f16)xp[(size_t)i * IN_H * IN_W];
    *reinterpret_cast<f16x8*>(Xn + ((size_t)(b * IN_H + y) * IN_W + x) * NCH + c0) =
        *reinterpret_cast<f16x8*>(v);
}

// ---- main: A resident in VGPRs; each wave-pair does 2 consecutive y -------
__global__ __launch_bounds__(256, 2)
void sconv_mfma(const f16* __restrict__ Ah, const f16* __restrict__ Xn,
                const float* __restrict__ Bg, float* __restrict__ Og)
{
    const int tid  = threadIdx.x;
    const int wave = tid >> 6;
    const int lane = tid & 63;
    const int oh   = wave & 1;
    const int pair = wave >> 1;
    const int px   = lane & 31;
    const int kg   = lane >> 5;

    // XCD-bijective chunk swizzle: 576 = 8 XCDs x 72 contiguous blocks (3 strips).
    const int wg = (blockIdx.x & 7) * 72 + (blockIdx.x >> 3);
    const int p  = wg * 2 + pair;          // pair index in [0, 1152)
    const int strip = p / RUNS;            // 0..23  (b, xg)
    const int run   = p - strip * RUNS;    // 0..47  -> y0 = 2*run
    const int b  = strip / 3;
    const int xg = strip - b * 3;
    const int x0 = xg * 32;
    const int y0 = run * 2;

    // A fragments: 27 nonzero (khw, j) per o-half, 16B/lane (108 VGPR)
    f16x8 A[9][3];
    {
        const f16* Ab = Ah + (size_t)oh * 27 * 64 * 8;
#pragma unroll
        for (int khw = 0; khw < 9; ++khw)
#pragma unroll
            for (int j = 0; j < 3; ++j)
                A[khw][j] = *reinterpret_cast<const f16x8*>(
                    Ab + (((size_t)khw * 3 + j) * 64 + lane) * 8);
    }
    // B c-offsets (f16 elems) for the 3 live c-blocks of this o-half
    int co[3];
    co[0] = 0; co[1] = oh ? 32 : 16; co[2] = oh ? 48 : 32;

    // bias in C/D row order: o = oh*32 + (r&3) + 8*(r>>2) + 4*kg
    float bv[16];
#pragma unroll
    for (int r = 0; r < 16; ++r)
        bv[r] = Bg[oh * 32 + (r & 3) + 8 * (r >> 2) + 4 * kg];

    const int x   = x0 + px;
    const bool ok = (x < OUT_W);

#pragma unroll
    for (int yy = 0; yy < 2; ++yy) {
        const int y = y0 + yy;
        if (y >= OUT_H) break;             // wave-uniform (pad run only)

        f32x16 acc;
#pragma unroll
        for (int r = 0; r < 16; ++r) acc[r] = bv[r];

#pragma unroll
        for (int kh = 0; kh < 3; ++kh) {
            const f16* rp = Xn + ((size_t)(b * IN_H + (y + kh)) * IN_W) * NCH;
#pragma unroll
            for (int kw = 0; kw < 3; ++kw) {
                const f16* cp = rp + (size_t)(x0 + kw + px) * NCH + kg * 8;
                f16x8 bf[3];
#pragma unroll
                for (int j = 0; j < 3; ++j)
                    bf[j] = *reinterpret_cast<const f16x8*>(cp + co[j]);
#pragma unroll
                for (int j = 0; j < 3; ++j)
                    acc = __builtin_amdgcn_mfma_f32_32x32x16_f16(
                              A[kh * 3 + kw][j], bf[j], acc, 0, 0, 0);
            }
        }

        if (ok) {
#pragma unroll
            for (int r = 0; r < 16; ++r) {
                const int o = oh * 32 + (r & 3) + 8 * (r >> 2) + 4 * kg;
                Og[(((size_t)b * NOC + o) * OUT_H + y) * OUT_W + x] = acc[r];
            }
        }
    }
}

// ---- fallback (round-5 proven VALU kernel) if ws too small -----------------
constexpr int TILE_X = 16, TILE_Y = 4, ROWS = TILE_Y + 2, COLS = 19;
__global__ __launch_bounds__(256, 4)
void sconv_kernel(const float* __restrict__ Xg, const float* __restrict__ Wg,
                  const float* __restrict__ Bg, float* __restrict__ Og)
{
    __shared__ float Xs[NCH][ROWS][COLS];
    const int tid = threadIdx.x, wave = tid >> 6, lane = tid & 63;
    const int x = lane & 15, y4 = lane >> 4;
    const int tx0 = blockIdx.x * TILE_X, ty0 = blockIdx.y * TILE_Y, b = blockIdx.z;
    const float* __restrict__ Xb = Xg + (size_t)b * NCH * IN_H * IN_W;
    for (int e = tid; e < NCH * ROWS * 9; e += 256) {
        const int c = e / (ROWS * 9), rm = e - c * (ROWS * 9), r = rm / 9, c2 = rm - r * 9;
        int gy = ty0 + r;      if (gy > IN_H - 1) gy = IN_H - 1;
        int gx = tx0 + 2 * c2; if (gx > IN_W - 2) gx = IN_W - 2;
        const float2 v = *reinterpret_cast<const float2*>(Xb + (c * IN_H + gy) * IN_W + gx);
        Xs[c][r][2 * c2] = v.x; Xs[c][r][2 * c2 + 1] = v.y;
    }
    __syncthreads();
    float acc[16];
#pragma unroll
    for (int i = 0; i < 16; ++i) acc[i] = 0.f;
    const int o_base = __builtin_amdgcn_readfirstlane(wave << 4);
    for (int dd = 0; dd < 31; ++dd) {
        const int c = (o_base + dd) & 63;
        float xv[3][3];
#pragma unroll
        for (int r = 0; r < 3; ++r)
#pragma unroll
            for (int kw = 0; kw < 3; ++kw) xv[r][kw] = Xs[c][y4 + r][x + kw];
#pragma unroll
        for (int jp = 0; jp < 16; ++jp)
            if ((unsigned)(dd - jp) < 16u) {
                const float* __restrict__ wp = Wg + (((o_base + jp) * NSUB) + (dd - jp)) * 9;
#pragma unroll
                for (int kh = 0; kh < 3; ++kh)
#pragma unroll
                    for (int kw = 0; kw < 3; ++kw)
                        acc[jp] = fmaf(wp[kh * 3 + kw], xv[kh][kw], acc[jp]);
            }
    }
    const int y = ty0 + y4, xo = tx0 + x;
    if (y < OUT_H && xo < OUT_W)
#pragma unroll
        for (int jp = 0; jp < 16; ++jp) {
            const int o = o_base + jp;
            Og[(((size_t)b * NOC + o) * OUT_H + y) * OUT_W + xo] = acc[jp] + Bg[o];
        }
}

extern "C" void kernel_launch(void* const* d_in, const int* in_sizes, int n_in,
                              void* d_out, int out_size, void* d_ws, size_t ws_size,
                              hipStream_t stream)
{
    const float* X = (const float*)d_in[0];
    const float* W = (const float*)d_in[1];
    const float* B = (const float*)d_in[2];
    float* O = (float*)d_out;

    if (ws_size < WS_NEEDED) {   // fallback: proven VALU kernel
        dim3 grid((OUT_W + TILE_X - 1) / TILE_X, (OUT_H + TILE_Y - 1) / TILE_Y, BATCH);
        sconv_kernel<<<grid, 256, 0, stream>>>(X, W, B, O);
        return;
    }

    f16* Ah = (f16*)d_ws;
    f16* Xn = (f16*)((char*)d_ws + XN_OFF);

    build_a_k<<<14, 256, 0, stream>>>(W, Ah);
    transpose_k<<<BATCH * IN_H * 3, 256, 0, stream>>>(X, Xn);
    sconv_mfma<<<NBLK, 256, 0, stream>>>(Ah, Xn, B, O);   // 576 blocks
}

// Round 10
// 92.053 us; speedup vs baseline: 1.0903x; 1.0903x over previous
//
#include <hip/hip_runtime.h>

// out[b,o,y,x] = bias[o] + sum_{s<16,kh,kw} W[o,s,kh,kw] * X[b,(o+s)%64,y+kh,x+kw]
// Fused: stage X patch NCHW->LDS (fp16, c-contiguous, XOR-swizzled), banded MFMA.
// Band touches 6 of 8 (oh,cs) 32x16 blocks: oh0->cs{0,1,2}, oh1->cs{0,2,3}.

typedef _Float16 f16;
typedef _Float16 f16x8 __attribute__((ext_vector_type(8)));
typedef float    f32x16 __attribute__((ext_vector_type(16)));

constexpr int IN_H = 96, IN_W = 96, OUT_H = 94, OUT_W = 94;
constexpr int NCH = 64, NOC = 64, NSUB = 16, BATCH = 8;
constexpr int TILE_Y = 4;                 // output rows per block
constexpr int SROWS  = TILE_Y + 2;        // 6 staged input rows
constexpr int SXP    = 36;                // staged x extent (32 + 2 halo + pad)
constexpr size_t A_BYTES   = 2ull * 27 * 64 * 16;   // 55296
constexpr size_t WS_NEEDED = A_BYTES + 256;

__device__ __forceinline__ int imin(int a, int b) { return a < b ? a : b; }

// ---- prologue: band matrices, A-frag lane layout, zero-blocks skipped ------
// A-frag (32x32x16): lane l holds row o=(l&31), k=(l>>5)*8+j.
__global__ void build_a_k(const float* __restrict__ W, f16* __restrict__ Ah)
{
    const int e = blockIdx.x * 256 + threadIdx.x;     // 2*27*64 = 3456 granules
    if (e >= 2 * 27 * 64) return;
    const int lane = e & 63;
    const int r    = e >> 6;          // oh*27 + khw*3 + j
    const int j    = r % 3;
    const int khw  = (r / 3) % 9;
    const int oh   = r / 27;
    const int cs   = oh ? (j == 0 ? 0 : j + 1) : j;   // oh0:{0,1,2} oh1:{0,2,3}
    const int kh = khw / 3, kw = khw % 3;
    const int o  = oh * 32 + (lane & 31);
    const int cb = cs * 16 + (lane >> 5) * 8;
    f16 v[8];
#pragma unroll
    for (int jj = 0; jj < 8; ++jj) {
        const int c = cb + jj;
        const int s = (c - o) & 63;
        v[jj] = (s < NSUB) ? (f16)W[((o * NSUB + s) * 3 + kh) * 3 + kw] : (f16)0.f;
    }
    *reinterpret_cast<f16x8*>(Ah + (size_t)e * 8) = *reinterpret_cast<f16x8*>(v);
}

// ---- fused main ------------------------------------------------------------
// LDS layout: byte(row, x, c) = ((row*SXP + x) << 7) + (((c>>3) ^ (x&7)) << 4)
//             + ((c&7) << 1)   -- 16B granule XOR spreads the 128B c-line
//             stride across banks (32-way -> ~4-way conflict).
__global__ __launch_bounds__(512, 2)
void sconv_fused(const float* __restrict__ Xg, const f16* __restrict__ Ah,
                 const float* __restrict__ Bg, float* __restrict__ Og)
{
    __shared__ __attribute__((aligned(16))) unsigned char lds[SROWS * SXP * 128]; // 27648 B

    const int tid  = threadIdx.x;
    const int wave = tid >> 6;
    const int lane = tid & 63;

    const int x0 = blockIdx.x * 32;       // 3 strips
    const int y0 = blockIdx.y * TILE_Y;   // 24 y-tiles
    const int b  = blockIdx.z;

    const float* __restrict__ Xb = Xg + (size_t)b * NCH * IN_H * IN_W;

    // ---- stage: rows y0..y0+5 (clamped), x0..x0+35 (clamped), all 64 ch ----
    {
        const int xh = tid & 31;          // x lane
        const int u  = tid >> 5;          // 0..15
        const int cg = u & 7;             // c-granule 0..7
        const int rb = u >> 3;            // 0..1 -> rows rb*3..rb*3+2
#pragma unroll
        for (int rr = 0; rr < 3; ++rr) {
            const int row = rb * 3 + rr;
            const int gy  = imin(y0 + row, IN_H - 1);
#pragma unroll
            for (int ci = 0; ci < 8; ++ci) {
                const int c = cg * 8 + ci;
                const float* __restrict__ p = Xb + ((size_t)c * IN_H + gy) * IN_W;
                const float f = p[imin(x0 + xh, IN_W - 1)];
                *reinterpret_cast<f16*>(lds + (((row * SXP + xh) << 7) +
                    ((cg ^ (xh & 7)) << 4) + (ci << 1))) = (f16)f;
                if (xh < 4) {
                    const int x2 = 32 + xh;
                    const float f2 = p[imin(x0 + x2, IN_W - 1)];
                    *reinterpret_cast<f16*>(lds + (((row * SXP + x2) << 7) +
                        ((cg ^ (x2 & 7)) << 4) + (ci << 1))) = (f16)f2;
                }
            }
        }
    }
    __syncthreads();

    // ---- compute: wave -> (oh, y row) --------------------------------------
    const int oh = wave & 1;
    const int yy = wave >> 1;             // 0..3
    const int y  = y0 + yy;
    if (y >= OUT_H) return;               // wave-uniform (pad tile only)

    const int px = lane & 31;
    const int kg = lane >> 5;

    // A fragments: 27 nonzero (khw, j), 16B/lane (108 VGPR)
    f16x8 A[9][3];
    {
        const f16* Ab = Ah + (size_t)oh * 27 * 64 * 8;
#pragma unroll
        for (int khw = 0; khw < 9; ++khw)
#pragma unroll
            for (int j = 0; j < 3; ++j)
                A[khw][j] = *reinterpret_cast<const f16x8*>(
                    Ab + (((size_t)khw * 3 + j) * 64 + lane) * 8);
    }
    // live c-granule bases for this o-half (granule = c/8): cs*2
    int cog[3];
    cog[0] = 0; cog[1] = oh ? 4 : 2; cog[2] = oh ? 6 : 4;

    // acc = bias (C/D row: o = oh*32 + (r&3) + 8*(r>>2) + 4*kg)
    f32x16 acc;
#pragma unroll
    for (int r = 0; r < 16; ++r)
        acc[r] = Bg[oh * 32 + (r & 3) + 8 * (r >> 2) + 4 * kg];

#pragma unroll
    for (int kh = 0; kh < 3; ++kh) {
#pragma unroll
        for (int kw = 0; kw < 3; ++kw) {
            const int xloc = px + kw;
            const int base = ((yy + kh) * SXP + xloc) << 7;
            const int sx   = xloc & 7;
            f16x8 bf[3];
#pragma unroll
            for (int j = 0; j < 3; ++j)
                bf[j] = *reinterpret_cast<const f16x8*>(
                    lds + base + (((cog[j] + kg) ^ sx) << 4));
#pragma unroll
            for (int j = 0; j < 3; ++j)
                acc = __builtin_amdgcn_mfma_f32_32x32x16_f16(
                          A[kh * 3 + kw][j], bf[j], acc, 0, 0, 0);
        }
    }

    const int x = x0 + px;
    if (x < OUT_W) {
#pragma unroll
        for (int r = 0; r < 16; ++r) {
            const int o = oh * 32 + (r & 3) + 8 * (r >> 2) + 4 * kg;
            Og[(((size_t)b * NOC + o) * OUT_H + y) * OUT_W + x] = acc[r];
        }
    }
}

// ---- fallback (round-5 proven VALU kernel) if ws too small -----------------
constexpr int TILE_Xf = 16, TILE_Yf = 4, ROWSf = TILE_Yf + 2, COLSf = 19;
__global__ __launch_bounds__(256, 4)
void sconv_kernel(const float* __restrict__ Xg, const float* __restrict__ Wg,
                  const float* __restrict__ Bg, float* __restrict__ Og)
{
    __shared__ float Xs[NCH][ROWSf][COLSf];
    const int tid = threadIdx.x, wave = tid >> 6, lane = tid & 63;
    const int x = lane & 15, y4 = lane >> 4;
    const int tx0 = blockIdx.x * TILE_Xf, ty0 = blockIdx.y * TILE_Yf, b = blockIdx.z;
    const float* __restrict__ Xb = Xg + (size_t)b * NCH * IN_H * IN_W;
    for (int e = tid; e < NCH * ROWSf * 9; e += 256) {
        const int c = e / (ROWSf * 9), rm = e - c * (ROWSf * 9), r = rm / 9, c2 = rm - r * 9;
        int gy = ty0 + r;      if (gy > IN_H - 1) gy = IN_H - 1;
        int gx = tx0 + 2 * c2; if (gx > IN_W - 2) gx = IN_W - 2;
        const float2 v = *reinterpret_cast<const float2*>(Xb + (c * IN_H + gy) * IN_W + gx);
        Xs[c][r][2 * c2] = v.x; Xs[c][r][2 * c2 + 1] = v.y;
    }
    __syncthreads();
    float acc[16];
#pragma unroll
    for (int i = 0; i < 16; ++i) acc[i] = 0.f;
    const int o_base = __builtin_amdgcn_readfirstlane(wave << 4);
    for (int dd = 0; dd < 31; ++dd) {
        const int c = (o_base + dd) & 63;
        float xv[3][3];
#pragma unroll
        for (int r = 0; r < 3; ++r)
#pragma unroll
            for (int kw = 0; kw < 3; ++kw) xv[r][kw] = Xs[c][y4 + r][x + kw];
#pragma unroll
        for (int jp = 0; jp < 16; ++jp)
            if ((unsigned)(dd - jp) < 16u) {
                const float* __restrict__ wp = Wg + (((o_base + jp) * NSUB) + (dd - jp)) * 9;
#pragma unroll
                for (int kh = 0; kh < 3; ++kh)
#pragma unroll
                    for (int kw = 0; kw < 3; ++kw)
                        acc[jp] = fmaf(wp[kh * 3 + kw], xv[kh][kw], acc[jp]);
            }
    }
    const int y = ty0 + y4, xo = tx0 + x;
    if (y < OUT_H && xo < OUT_W)
#pragma unroll
        for (int jp = 0; jp < 16; ++jp) {
            const int o = o_base + jp;
            Og[(((size_t)b * NOC + o) * OUT_H + y) * OUT_W + xo] = acc[jp] + Bg[o];
        }
}

extern "C" void kernel_launch(void* const* d_in, const int* in_sizes, int n_in,
                              void* d_out, int out_size, void* d_ws, size_t ws_size,
                              hipStream_t stream)
{
    const float* X = (const float*)d_in[0];
    const float* W = (const float*)d_in[1];
    const float* B = (const float*)d_in[2];
    float* O = (float*)d_out;

    if (ws_size < WS_NEEDED) {   // fallback: proven VALU kernel
        dim3 grid((OUT_W + TILE_Xf - 1) / TILE_Xf, (OUT_H + TILE_Yf - 1) / TILE_Yf, BATCH);
        sconv_kernel<<<grid, 256, 0, stream>>>(X, W, B, O);
        return;
    }

    f16* Ah = (f16*)d_ws;
    build_a_k<<<14, 256, 0, stream>>>(W, Ah);
    dim3 grid(3, (OUT_H + TILE_Y - 1) / TILE_Y, BATCH);   // 3 x 24 x 8 = 576
    sconv_fused<<<grid, 512, 0, stream>>>(X, Ah, B, O);
}

// Round 12
// 91.999 us; speedup vs baseline: 1.0910x; 1.0006x over previous
//
#include <hip/hip_runtime.h>

// out[b,o,y,x] = bias[o] + sum_{s<16,kh,kw} W[o,s,kh,kw] * X[b,(o+s)%64,y+kh,x+kw]
// Fused: stage X patch NCHW->LDS (fp16, c-contiguous, XOR-swizzled), banded MFMA.
// Band touches 6 of 8 (oh,cs) 32x16 blocks: oh0->cs{0,1,2}, oh1->cs{0,2,3}.

typedef _Float16 f16;
typedef _Float16 f16x8 __attribute__((ext_vector_type(8)));
typedef float    f32x16 __attribute__((ext_vector_type(16)));

constexpr int IN_H = 96, IN_W = 96, OUT_H = 94, OUT_W = 94;
constexpr int NCH = 64, NOC = 64, NSUB = 16, BATCH = 8;
constexpr int TILE_Y = 2;                 // output rows per block (47 tiles, no y clamps)
constexpr int SROWS  = TILE_Y + 2;        // 4 staged input rows
constexpr int SXP    = 36;                // staged x extent (32 + 2 halo + pad)
constexpr size_t A_BYTES   = 2ull * 27 * 64 * 16;   // 55296
constexpr size_t WS_NEEDED = A_BYTES + 256;

// ---- prologue: band matrices, A-frag lane layout, zero-blocks skipped ------
// A-frag (32x32x16): lane l holds row o=(l&31), k=(l>>5)*8+j.
__global__ void build_a_k(const float* __restrict__ W, f16* __restrict__ Ah)
{
    const int e = blockIdx.x * 256 + threadIdx.x;     // 2*27*64 = 3456 granules
    if (e >= 2 * 27 * 64) return;
    const int lane = e & 63;
    const int r    = e >> 6;          // oh*27 + khw*3 + j
    const int j    = r % 3;
    const int khw  = (r / 3) % 9;
    const int oh   = r / 27;
    const int cs   = oh ? (j == 0 ? 0 : j + 1) : j;   // oh0:{0,1,2} oh1:{0,2,3}
    const int kh = khw / 3, kw = khw % 3;
    const int o  = oh * 32 + (lane & 31);
    const int cb = cs * 16 + (lane >> 5) * 8;
    f16 v[8];
#pragma unroll
    for (int jj = 0; jj < 8; ++jj) {
        const int c = cb + jj;
        const int s = (c - o) & 63;
        v[jj] = (s < NSUB) ? (f16)W[((o * NSUB + s) * 3 + kh) * 3 + kw] : (f16)0.f;
    }
    *reinterpret_cast<f16x8*>(Ah + (size_t)e * 8) = *reinterpret_cast<f16x8*>(v);
}

// ---- fused main ------------------------------------------------------------
// LDS layout: byte(row, x, c) = ((row*SXP + x) << 7) + (((c>>3) ^ (x&7)) << 4)
//             + ((c&7) << 1)   -- 16B-granule XOR spreads the 128B c-line stride.
__global__ __launch_bounds__(256, 3)
void sconv_fused(const float* __restrict__ Xg, const f16* __restrict__ Ah,
                 const float* __restrict__ Bg, float* __restrict__ Og)
{
    __shared__ __attribute__((aligned(16))) unsigned char lds[SROWS * SXP * 128]; // 18432 B

    const int tid  = threadIdx.x;
    const int wave = tid >> 6;
    const int lane = tid & 63;
    const int oh   = wave & 1;
    const int yy   = wave >> 1;           // 0..1
    const int px   = lane & 31;
    const int kg   = lane >> 5;

    const int x0 = blockIdx.x * 32;       // 3 strips
    const int y0 = blockIdx.y * TILE_Y;   // 47 y-tiles: y0 <= 92, staged rows <= 95
    const int b  = blockIdx.z;

    // 1) A-frag loads FIRST: latency hides under the staging loop.
    //    27 nonzero (khw, j) fragments per o-half, 16B/lane (108 VGPR).
    f16x8 A[9][3];
    {
        const f16* Ab = Ah + (size_t)oh * 27 * 64 * 8;
#pragma unroll
        for (int khw = 0; khw < 9; ++khw)
#pragma unroll
            for (int j = 0; j < 3; ++j)
                A[khw][j] = *reinterpret_cast<const f16x8*>(
                    Ab + (((size_t)khw * 3 + j) * 64 + lane) * 8);
    }

    // 2) stage: thread owns one (c,row) line; 9 float4 loads, 36 f16 LDS writes.
    {
        const int c   = tid >> 2;         // 0..63
        const int row = tid & 3;          // 0..3
        const int g   = c >> 3, cl = c & 7;
        const float* __restrict__ p =
            Xg + (((size_t)b * NCH + c) * IN_H + (y0 + row)) * IN_W;
#pragma unroll
        for (int i = 0; i < 9; ++i) {
            const int xs = 4 * i;
            int gx = x0 + xs; if (gx > IN_W - 4) gx = IN_W - 4;   // strip 2, i==8 only:
            const float4 v = *reinterpret_cast<const float4*>(p + gx); // slots 32..35 feed
            const float vv[4] = {v.x, v.y, v.z, v.w};                  // discarded px>=30 only
#pragma unroll
            for (int q = 0; q < 4; ++q) {
                const int xl = xs + q;
                *reinterpret_cast<f16*>(lds + (((row * SXP + xl) << 7) +
                    ((g ^ (xl & 7)) << 4) + (cl << 1))) = (f16)vv[q];
            }
        }
    }
    __syncthreads();

    // live c-granule bases for this o-half (granule = c/8): cs*2
    int cog[3];
    cog[0] = 0; cog[1] = oh ? 4 : 2; cog[2] = oh ? 6 : 4;

    f32x16 acc;
#pragma unroll
    for (int r = 0; r < 16; ++r) acc[r] = 0.f;

#pragma unroll
    for (int kh = 0; kh < 3; ++kh) {
#pragma unroll
        for (int kw = 0; kw < 3; ++kw) {
            const int xloc = px + kw;
            const int base = ((yy + kh) * SXP + xloc) << 7;
            const int sx   = xloc & 7;
            f16x8 bf[3];
#pragma unroll
            for (int j = 0; j < 3; ++j)
                bf[j] = *reinterpret_cast<const f16x8*>(
                    lds + base + (((cog[j] + kg) ^ sx) << 4));
#pragma unroll
            for (int j = 0; j < 3; ++j)
                acc = __builtin_amdgcn_mfma_f32_32x32x16_f16(
                          A[kh * 3 + kw][j], bf[j], acc, 0, 0, 0);
        }
    }

    // epilogue: bias added here (no bv[16] held across kernel -> lower VGPR)
    const int y = y0 + yy;                // always < OUT_H (47*2 = 94)
    const int x = x0 + px;
    if (x < OUT_W) {
#pragma unroll
        for (int r = 0; r < 16; ++r) {
            const int o = oh * 32 + (r & 3) + 8 * (r >> 2) + 4 * kg;
            Og[(((size_t)b * NOC + o) * OUT_H + y) * OUT_W + x] = acc[r] + Bg[o];
        }
    }
}

// ---- fallback (round-5 proven VALU kernel) if ws too small -----------------
constexpr int TILE_Xf = 16, TILE_Yf = 4, ROWSf = TILE_Yf + 2, COLSf = 19;
__global__ __launch_bounds__(256, 4)
void sconv_kernel(const float* __restrict__ Xg, const float* __restrict__ Wg,
                  const float* __restrict__ Bg, float* __restrict__ Og)
{
    __shared__ float Xs[NCH][ROWSf][COLSf];
    const int tid = threadIdx.x, wave = tid >> 6, lane = tid & 63;
    const int x = lane & 15, y4 = lane >> 4;
    const int tx0 = blockIdx.x * TILE_Xf, ty0 = blockIdx.y * TILE_Yf, b = blockIdx.z;
    const float* __restrict__ Xb = Xg + (size_t)b * NCH * IN_H * IN_W;
    for (int e = tid; e < NCH * ROWSf * 9; e += 256) {
        const int c = e / (ROWSf * 9), rm = e - c * (ROWSf * 9), r = rm / 9, c2 = rm - r * 9;
        int gy = ty0 + r;      if (gy > IN_H - 1) gy = IN_H - 1;
        int gx = tx0 + 2 * c2; if (gx > IN_W - 2) gx = IN_W - 2;
        const float2 v = *reinterpret_cast<const float2*>(Xb + (c * IN_H + gy) * IN_W + gx);
        Xs[c][r][2 * c2] = v.x; Xs[c][r][2 * c2 + 1] = v.y;
    }
    __syncthreads();
    float acc[16];
#pragma unroll
    for (int i = 0; i < 16; ++i) acc[i] = 0.f;
    const int o_base = __builtin_amdgcn_readfirstlane(wave << 4);
    for (int dd = 0; dd < 31; ++dd) {
        const int c = (o_base + dd) & 63;
        float xv[3][3];
#pragma unroll
        for (int r = 0; r < 3; ++r)
#pragma unroll
            for (int kw = 0; kw < 3; ++kw) xv[r][kw] = Xs[c][y4 + r][x + kw];
#pragma unroll
        for (int jp = 0; jp < 16; ++jp)
            if ((unsigned)(dd - jp) < 16u) {
                const float* __restrict__ wp = Wg + (((o_base + jp) * NSUB) + (dd - jp)) * 9;
#pragma unroll
                for (int kh = 0; kh < 3; ++kh)
#pragma unroll
                    for (int kw = 0; kw < 3; ++kw)
                        acc[jp] = fmaf(wp[kh * 3 + kw], xv[kh][kw], acc[jp]);
            }
    }
    const int y = ty0 + y4, xo = tx0 + x;
    if (y < OUT_H && xo < OUT_W)
#pragma unroll
        for (int jp = 0; jp < 16; ++jp) {
            const int o = o_base + jp;
            Og[(((size_t)b * NOC + o) * OUT_H + y) * OUT_W + xo] = acc[jp] + Bg[o];
        }
}

extern "C" void kernel_launch(void* const* d_in, const int* in_sizes, int n_in,
                              void* d_out, int out_size, void* d_ws, size_t ws_size,
                              hipStream_t stream)
{
    const float* X = (const float*)d_in[0];
    const float* W = (const float*)d_in[1];
    const float* B = (const float*)d_in[2];
    float* O = (float*)d_out;

    if (ws_size < WS_NEEDED) {   // fallback: proven VALU kernel
        dim3 grid((OUT_W + TILE_Xf - 1) / TILE_Xf, (OUT_H + TILE_Yf - 1) / TILE_Yf, BATCH);
        sconv_kernel<<<grid, 256, 0, stream>>>(X, W, B, O);
        return;
    }

    f16* Ah = (f16*)d_ws;
    build_a_k<<<14, 256, 0, stream>>>(W, Ah);
    dim3 grid(3, OUT_H / TILE_Y, BATCH);   // 3 x 47 x 8 = 1128
    sconv_fused<<<grid, 256, 0, stream>>>(X, Ah, B, O);
}